// Round 6
// baseline (738.772 us; speedup 1.0000x reference)
//
#include <hip/hip_runtime.h>

typedef __attribute__((ext_vector_type(8))) short bf16x8;
typedef __attribute__((ext_vector_type(4))) float f32x4;

#define HID 768
#define NH 12
#define HD 64

#if defined(__has_builtin)
#  if __has_builtin(__builtin_amdgcn_exp2f)
#    define EXP2(x) __builtin_amdgcn_exp2f(x)
#  endif
#endif
#ifndef EXP2
#  define EXP2(x) exp2f(x)
#endif

#if defined(__has_builtin)
#  if __has_builtin(__builtin_amdgcn_fdot2_f32_bf16)
#    define HAVE_DOT2 1
#  endif
#endif
#ifndef HAVE_DOT2
#  define HAVE_DOT2 0
#endif

// q pre-scale: HEAD_DIM^-0.5 * log2(e)  -> scores land in log2 domain
#define QSCALE 0.18033688011112042f

__device__ inline float b2f(unsigned short x) {
  return __builtin_bit_cast(float, ((unsigned)x) << 16);
}
__device__ inline unsigned short f2b(float f) {
  unsigned u = __builtin_bit_cast(unsigned, f);
  u += 0x7fffu + ((u >> 16) & 1u);  // RNE
  return (unsigned short)(u >> 16);
}

#if HAVE_DOT2
typedef __attribute__((ext_vector_type(2))) __bf16 bf16v2;
__device__ inline float dot8q(bf16x8 q, bf16x8 k, float acc) {
  union { bf16x8 v; bf16v2 p[4]; } qa, ka;
  qa.v = q; ka.v = k;
  float s = acc;
#pragma unroll
  for (int i = 0; i < 4; ++i)
    s = __builtin_amdgcn_fdot2_f32_bf16(qa.p[i], ka.p[i], s, false);
  return s;
}
#else
__device__ inline float dot8f(const float qf[8], bf16x8 k, float acc) {
#pragma unroll
  for (int i = 0; i < 8; ++i) acc += qf[i] * b2f((unsigned short)k[i]);
  return acc;
}
#endif

// ---------------- cast fp32 -> bf16 (vectorized) ----------------
__global__ __launch_bounds__(256) void cast_bf16(const float* __restrict__ in,
                                                 unsigned short* __restrict__ out, int n4) {
  int t = blockIdx.x * 256 + threadIdx.x;
  if (t >= n4) return;
  float4 v = ((const float4*)in)[t];
  ushort4 o;
  o.x = f2b(v.x); o.y = f2b(v.y); o.z = f2b(v.z); o.w = f2b(v.w);
  ((ushort4*)out)[t] = o;
}

// ---------------- weight prep: permute rows to head-major, cast bf16 ----------------
__global__ __launch_bounds__(256) void prep_weights(
    const float* __restrict__ Wq, const float* __restrict__ Wk,
    const float* __restrict__ Wv, const float* __restrict__ Wo,
    unsigned short* __restrict__ wq, unsigned short* __restrict__ wkv,
    unsigned short* __restrict__ wo) {
  int mat = blockIdx.y;
  int o = blockIdx.x * 256 + threadIdx.x;  // < 768*768
  int jrow = o / HID, c = o - jrow * HID;
  if (mat < 3) {
    int h = jrow >> 6, d = jrow & 63;
    const float* W = (mat == 0) ? Wq : ((mat == 1) ? Wk : Wv);
    float val = W[(d * NH + h) * HID + c];
    if (mat == 0) {
      wq[o] = f2b(val * QSCALE);
    } else if (mat == 1) {
      wkv[o] = f2b(val);
    } else {
      wkv[(size_t)HID * HID + o] = f2b(val);
    }
  } else {
    int h = c >> 6, d = c & 63;
    wo[o] = f2b(Wo[(size_t)jrow * HID + d * NH + h]);
  }
}

__global__ void prep_bias(const float* __restrict__ bq, const float* __restrict__ bk,
                          const float* __restrict__ bv, float* __restrict__ bqp,
                          float* __restrict__ bkvp) {
  int j = threadIdx.x;
  if (j >= HID) return;
  int h = j >> 6, d = j & 63, s = d * NH + h;
  bqp[j] = bq[s] * QSCALE;
  bkvp[j] = bk[s];
  bkvp[HID + j] = bv[s];
}

// ---------------- bf16 MFMA GEMM, 128x128 tile, BK=32, double-buffered prefetch ----------------
template <int OUT_F32>
__global__ __launch_bounds__(256) void gemm_nt(
    const unsigned short* __restrict__ A, const unsigned short* __restrict__ B,
    const float* __restrict__ bias, void* __restrict__ Cv, int M, int Nn, int K) {
  __shared__ __align__(16) unsigned short As[2][128 * 32];
  __shared__ __align__(16) unsigned short Bs[2][128 * 32];
  const int tid = threadIdx.x;
  const int lane = tid & 63;
  const int wid = tid >> 6;
  const int wr = wid >> 1, wc = wid & 1;
  const int l16 = lane & 15, kq = lane >> 4;
  const int m0 = blockIdx.x * 128;
  const int n0 = blockIdx.y * 128;

  f32x4 acc[4][4];
#pragma unroll
  for (int i = 0; i < 4; ++i)
#pragma unroll
    for (int j = 0; j < 4; ++j) acc[i][j] = (f32x4){0.f, 0.f, 0.f, 0.f};

  const int srow = tid >> 2;
  const int skg = tid & 3;
  const int scol = (skg ^ ((srow >> 1) & 3)) * 8;  // pre-swizzled source col
  const int sbase = (tid & ~63) * 8;               // wave-uniform LDS elem base

  const unsigned short* Ag = A + (size_t)(m0 + srow) * K + scol;
  const unsigned short* Bg = B + (size_t)(n0 + srow) * K + scol;
  const int kqA0 = (kq ^ ((l16 >> 1) & 3)) * 8;    // swizzled k-group for reads

#define STAGE(buf, kk)                                                                              \
  do {                                                                                              \
    __builtin_amdgcn_global_load_lds((const __attribute__((address_space(1))) void*)(Ag + (kk)),    \
                                     (__attribute__((address_space(3))) void*)(&As[buf][0] + sbase), 16, 0, 0); \
    __builtin_amdgcn_global_load_lds((const __attribute__((address_space(1))) void*)(Ag + (size_t)64 * K + (kk)), \
                                     (__attribute__((address_space(3))) void*)(&As[buf][0] + 2048 + sbase), 16, 0, 0); \
    __builtin_amdgcn_global_load_lds((const __attribute__((address_space(1))) void*)(Bg + (kk)),    \
                                     (__attribute__((address_space(3))) void*)(&Bs[buf][0] + sbase), 16, 0, 0); \
    __builtin_amdgcn_global_load_lds((const __attribute__((address_space(1))) void*)(Bg + (size_t)64 * K + (kk)), \
                                     (__attribute__((address_space(3))) void*)(&Bs[buf][0] + 2048 + sbase), 16, 0, 0); \
  } while (0)

  STAGE(0, 0);
  __syncthreads();
  int cur = 0;
  for (int k0 = 0; k0 < K; k0 += 32) {
    if (k0 + 32 < K) STAGE(cur ^ 1, k0 + 32);  // prefetch overlaps compute
    bf16x8 af[4], bfr[4];
#pragma unroll
    for (int i = 0; i < 4; ++i) {
      int ra = wr * 64 + i * 16 + l16;
      af[i] = *(const bf16x8*)(&As[cur][0] + ra * 32 + kqA0);
      int rb = wc * 64 + i * 16 + l16;
      bfr[i] = *(const bf16x8*)(&Bs[cur][0] + rb * 32 + kqA0);
    }
#pragma unroll
    for (int mi = 0; mi < 4; ++mi)
#pragma unroll
      for (int ni = 0; ni < 4; ++ni)
        acc[mi][ni] = __builtin_amdgcn_mfma_f32_16x16x32_bf16(af[mi], bfr[ni], acc[mi][ni], 0, 0, 0);
    __syncthreads();
    cur ^= 1;
  }
#undef STAGE

  float* Cf = (float*)Cv;
  unsigned short* Cb = (unsigned short*)Cv;
#pragma unroll
  for (int mi = 0; mi < 4; ++mi) {
    int grow = m0 + wr * 64 + mi * 16 + kq * 4;
#pragma unroll
    for (int ni = 0; ni < 4; ++ni) {
      int gcol = n0 + wc * 64 + ni * 16 + l16;
      float bv_ = bias[gcol];
#pragma unroll
      for (int r = 0; r < 4; ++r) {
        float v = acc[mi][ni][r] + bv_;
        if (OUT_F32)
          Cf[(size_t)(grow + r) * Nn + gcol] = v;
        else
          Cb[(size_t)(grow + r) * Nn + gcol] = f2b(v);
      }
    }
  }
}

// ---------------- rowptr from sorted row_idx ----------------
__global__ __launch_bounds__(256) void build_rowptr(const int* __restrict__ row_idx,
                                                    int* __restrict__ rowptr, int n, int E_) {
  int t = blockIdx.x * 256 + threadIdx.x;
  if (t > n) return;
  int lo = 0, hi = E_;
  while (lo < hi) {
    int mid = (lo + hi) >> 1;
    if (row_idx[mid] < t) lo = mid + 1; else hi = mid;
  }
  rowptr[t] = lo;
}

// ---------------- pass A (per head): k-gather scores + row max + NORMALIZED weights ----------------
// Wave per (row, head). 8 groups x 8 lanes; group g = edge, lane dl = dims dl*8..+8.
// Main loop: max-only. Epilogue: wave-coalesced re-read of the row's contiguous score
// segment (L1/L2-hot) -> wsum -> overwrite scores with exp2(s-m)/wsum (final attn weights).
__global__ __launch_bounds__(256) void edge_scores(const int* __restrict__ rowptr,
                                                   const int* __restrict__ col_idx,
                                                   const unsigned short* __restrict__ q,
                                                   const unsigned short* __restrict__ kv,
                                                   float* __restrict__ scores, int n, int E_) {
  int lane = threadIdx.x & 63;
  int head = blockIdx.y;
  int row = blockIdx.x * 4 + (threadIdx.x >> 6);
  if (row >= n) return;
  int s0 = rowptr[row], s1 = rowptr[row + 1];
  if (s0 >= s1) return;
  int g = lane >> 3, dl = lane & 7;

  bf16x8 qv = *(const bf16x8*)(q + (size_t)row * HID + head * HD + dl * 8);
#if !HAVE_DOT2
  float qf[8];
#pragma unroll
  for (int i = 0; i < 8; ++i) qf[i] = b2f((unsigned short)qv[i]);
#endif

  const unsigned short* kbase = kv + head * HD + dl * 8;
  float* sc = scores + (size_t)head * E_;
  float mg = -1e30f;
  int e0 = s0;
  for (; e0 + 16 <= s1; e0 += 16) {
    int ea = e0 + g, eb = e0 + 8 + g;
    int ca = col_idx[ea], cb = col_idx[eb];
    bf16x8 ka = *(const bf16x8*)(kbase + (size_t)ca * (2 * HID));
    bf16x8 kb = *(const bf16x8*)(kbase + (size_t)cb * (2 * HID));
#if HAVE_DOT2
    float da = dot8q(qv, ka, 0.f);
    float db = dot8q(qv, kb, 0.f);
#else
    float da = dot8f(qf, ka, 0.f);
    float db = dot8f(qf, kb, 0.f);
#endif
    da += __shfl_xor(da, 1); db += __shfl_xor(db, 1);
    da += __shfl_xor(da, 2); db += __shfl_xor(db, 2);
    da += __shfl_xor(da, 4); db += __shfl_xor(db, 4);
    if (dl == 0) { sc[ea] = da; sc[eb] = db; }
    mg = fmaxf(mg, fmaxf(da, db));  // -> v_max3
  }
  for (; e0 < s1; e0 += 8) {
    int e = e0 + g;
    bool valid = e < s1;
    int c = col_idx[valid ? e : s0];
    bf16x8 kc = *(const bf16x8*)(kbase + (size_t)c * (2 * HID));
#if HAVE_DOT2
    float d = dot8q(qv, kc, 0.f);
#else
    float d = dot8f(qf, kc, 0.f);
#endif
    d += __shfl_xor(d, 1);
    d += __shfl_xor(d, 2);
    d += __shfl_xor(d, 4);
    if (valid && dl == 0) sc[e] = d;
    mg = fmaxf(mg, valid ? d : -1e30f);
  }
  mg = fmaxf(mg, __shfl_xor(mg, 8));
  mg = fmaxf(mg, __shfl_xor(mg, 16));
  mg = fmaxf(mg, __shfl_xor(mg, 32));

  // epilogue: normalize the row segment in place (coalesced, cache-hot)
  float wsum = 0.f;
  for (int e = s0 + lane; e < s1; e += 64) wsum += EXP2(sc[e] - mg);
  wsum += __shfl_xor(wsum, 1);
  wsum += __shfl_xor(wsum, 2);
  wsum += __shfl_xor(wsum, 4);
  wsum += __shfl_xor(wsum, 8);
  wsum += __shfl_xor(wsum, 16);
  wsum += __shfl_xor(wsum, 32);
  float inv = 1.f / wsum;
  for (int e = s0 + lane; e < s1; e += 64) sc[e] = EXP2(sc[e] - mg) * inv;
}

// ---------------- pass B (per head): pure weighted v-gather accumulate ----------------
__global__ __launch_bounds__(256) void edge_spmm(const int* __restrict__ rowptr,
                                                 const int* __restrict__ col_idx,
                                                 const float* __restrict__ scores,
                                                 const unsigned short* __restrict__ kv,
                                                 unsigned short* __restrict__ out, int n, int E_) {
  int lane = threadIdx.x & 63;
  int head = blockIdx.y;
  int row = blockIdx.x * 4 + (threadIdx.x >> 6);
  if (row >= n) return;
  int s0 = rowptr[row], s1 = rowptr[row + 1];
  int g = lane >> 3, dl = lane & 7;
  const float* sc = scores + (size_t)head * E_;
  const unsigned short* vbase = kv + HID + head * HD + dl * 8;

  float acc[8] = {};
  int e0 = s0;
  for (; e0 + 16 <= s1; e0 += 16) {
    int ea = e0 + g, eb = e0 + 8 + g;
    int ca = col_idx[ea], cb = col_idx[eb];
    float wa = sc[ea];
    float wb = sc[eb];
    bf16x8 va = *(const bf16x8*)(vbase + (size_t)ca * (2 * HID));
    bf16x8 vb = *(const bf16x8*)(vbase + (size_t)cb * (2 * HID));
#pragma unroll
    for (int i = 0; i < 8; ++i) {
      acc[i] += wa * b2f((unsigned short)va[i]);
      acc[i] += wb * b2f((unsigned short)vb[i]);
    }
  }
  for (; e0 < s1; e0 += 8) {
    int e = e0 + g;
    bool valid = e < s1;
    int ec = valid ? e : s0;
    int c = col_idx[ec];
    float w = valid ? sc[ec] : 0.f;
    bf16x8 vc = *(const bf16x8*)(vbase + (size_t)c * (2 * HID));
#pragma unroll
    for (int i = 0; i < 8; ++i) acc[i] += w * b2f((unsigned short)vc[i]);
  }
#pragma unroll
  for (int i = 0; i < 8; ++i) {
    acc[i] += __shfl_xor(acc[i], 8);
    acc[i] += __shfl_xor(acc[i], 16);
    acc[i] += __shfl_xor(acc[i], 32);
  }
  if (g == 0) {
    short o[8];
#pragma unroll
    for (int i = 0; i < 8; ++i) o[i] = (short)f2b(acc[i]);
    *(bf16x8*)(out + (size_t)row * HID + head * HD + dl * 8) = *(bf16x8*)o;
  }
}

// ---------------- launch ----------------
extern "C" void kernel_launch(void* const* d_in, const int* in_sizes, int n_in,
                              void* d_out, int out_size, void* d_ws, size_t ws_size,
                              hipStream_t stream) {
  const float* h_source = (const float*)d_in[0];
  const float* h_target = (const float*)d_in[1];
  const int* row_idx = (const int*)d_in[2];
  const int* col_idx = (const int*)d_in[3];
  const float* Wq = (const float*)d_in[4];
  const float* bq = (const float*)d_in[5];
  const float* Wk = (const float*)d_in[6];
  const float* bk = (const float*)d_in[7];
  const float* Wv = (const float*)d_in[8];
  const float* bv = (const float*)d_in[9];
  const float* Wo = (const float*)d_in[10];
  const float* bo = (const float*)d_in[11];
  float* out = (float*)d_out;

  const int n = in_sizes[0] / HID;   // 32768
  const int E_ = in_sizes[2];        // 1048576

  char* ws = (char*)d_ws;
  size_t off = 0;
  auto alloc = [&](size_t bytes) -> void* {
    off = (off + 255) & ~(size_t)255;
    void* p = ws + off;
    off += bytes;
    return p;
  };
  unsigned short* htb = (unsigned short*)alloc((size_t)n * HID * 2);   // h_target bf16
  unsigned short* hsb = (unsigned short*)alloc((size_t)n * HID * 2);   // h_source bf16
  unsigned short* qb = (unsigned short*)alloc((size_t)n * HID * 2);    // q; attn_out in-place
  unsigned short* kvb = (unsigned short*)alloc((size_t)n * 2 * HID * 2);  // kv interleaved
  float* scores = (float*)alloc((size_t)NH * E_ * 4);                  // per-head planes
  unsigned short* wqp = (unsigned short*)alloc((size_t)HID * HID * 2);
  unsigned short* wkvp = (unsigned short*)alloc((size_t)2 * HID * HID * 2);
  unsigned short* wop = (unsigned short*)alloc((size_t)HID * HID * 2);
  float* bqp = (float*)alloc(HID * 4);
  float* bkvp = (float*)alloc(2 * HID * 4);
  int* rowptr = (int*)alloc((size_t)(n + 1) * 4);

  int n4 = n * HID / 4;
  cast_bf16<<<(n4 + 255) / 256, 256, 0, stream>>>(h_target, htb, n4);
  cast_bf16<<<(n4 + 255) / 256, 256, 0, stream>>>(h_source, hsb, n4);
  prep_weights<<<dim3(HID * HID / 256, 4), 256, 0, stream>>>(Wq, Wk, Wv, Wo, wqp, wkvp, wop);
  prep_bias<<<1, HID, 0, stream>>>(bq, bk, bv, bqp, bkvp);
  build_rowptr<<<(n + 1 + 255) / 256, 256, 0, stream>>>(row_idx, rowptr, n, E_);

  dim3 gq(n / 128, HID / 128);
  dim3 gkv(n / 128, 2 * HID / 128);
  gemm_nt<0><<<gq, 256, 0, stream>>>(htb, wqp, bqp, qb, n, HID, HID);
  gemm_nt<0><<<gkv, 256, 0, stream>>>(hsb, wkvp, bkvp, kvb, n, 2 * HID, HID);

  dim3 ge(n / 4, NH);
  edge_scores<<<ge, 256, 0, stream>>>(rowptr, col_idx, qb, kvb, scores, n, E_);
  edge_spmm<<<ge, 256, 0, stream>>>(rowptr, col_idx, scores, kvb, qb /* attn_out */, n, E_);

  gemm_nt<1><<<gq, 256, 0, stream>>>(qb, wop, bo, out, n, HID, HID);
}

// Round 7
// 642.326 us; speedup vs baseline: 1.1502x; 1.1502x over previous
//
#include <hip/hip_runtime.h>

typedef __attribute__((ext_vector_type(8))) short bf16x8;
typedef __attribute__((ext_vector_type(4))) float f32x4;

#define HID 768
#define NH 12
#define HD 64

#if defined(__has_builtin)
#  if __has_builtin(__builtin_amdgcn_exp2f)
#    define EXP2(x) __builtin_amdgcn_exp2f(x)
#  endif
#endif
#ifndef EXP2
#  define EXP2(x) exp2f(x)
#endif

// q pre-scale: HEAD_DIM^-0.5 * log2(e)  -> scores land in log2 domain
#define QSCALE 0.18033688011112042f

__device__ inline float b2f(unsigned short x) {
  return __builtin_bit_cast(float, ((unsigned)x) << 16);
}
__device__ inline unsigned short f2b(float f) {
  unsigned u = __builtin_bit_cast(unsigned, f);
  u += 0x7fffu + ((u >> 16) & 1u);  // RNE
  return (unsigned short)(u >> 16);
}

// ---------------- cast fp32 -> bf16 (vectorized) ----------------
__global__ __launch_bounds__(256) void cast_bf16(const float* __restrict__ in,
                                                 unsigned short* __restrict__ out, int n4) {
  int t = blockIdx.x * 256 + threadIdx.x;
  if (t >= n4) return;
  float4 v = ((const float4*)in)[t];
  ushort4 o;
  o.x = f2b(v.x); o.y = f2b(v.y); o.z = f2b(v.z); o.w = f2b(v.w);
  ((ushort4*)out)[t] = o;
}

// ---------------- weight prep: permute rows to head-major, cast bf16 ----------------
__global__ __launch_bounds__(256) void prep_weights(
    const float* __restrict__ Wq, const float* __restrict__ Wk,
    const float* __restrict__ Wv, const float* __restrict__ Wo,
    unsigned short* __restrict__ wq, unsigned short* __restrict__ wkv,
    unsigned short* __restrict__ wo) {
  int mat = blockIdx.y;
  int o = blockIdx.x * 256 + threadIdx.x;  // < 768*768
  int jrow = o / HID, c = o - jrow * HID;
  if (mat < 3) {
    int h = jrow >> 6, d = jrow & 63;
    const float* W = (mat == 0) ? Wq : ((mat == 1) ? Wk : Wv);
    float val = W[(d * NH + h) * HID + c];
    if (mat == 0) {
      wq[o] = f2b(val * QSCALE);
    } else if (mat == 1) {
      wkv[o] = f2b(val);
    } else {
      wkv[(size_t)HID * HID + o] = f2b(val);
    }
  } else {
    int h = c >> 6, d = c & 63;
    wo[o] = f2b(Wo[(size_t)jrow * HID + d * NH + h]);
  }
}

__global__ void prep_bias(const float* __restrict__ bq, const float* __restrict__ bk,
                          const float* __restrict__ bv, float* __restrict__ bqp,
                          float* __restrict__ bkvp) {
  int j = threadIdx.x;
  if (j >= HID) return;
  int h = j >> 6, d = j & 63, s = d * NH + h;
  bqp[j] = bq[s] * QSCALE;
  bkvp[j] = bk[s];
  bkvp[HID + j] = bv[s];
}

// ---------------- bf16 MFMA GEMM, 128x128 tile, BK=32, double-buffered prefetch ----------------
template <int OUT_F32>
__global__ __launch_bounds__(256) void gemm_nt(
    const unsigned short* __restrict__ A, const unsigned short* __restrict__ B,
    const float* __restrict__ bias, void* __restrict__ Cv, int M, int Nn, int K) {
  __shared__ __align__(16) unsigned short As[2][128 * 32];
  __shared__ __align__(16) unsigned short Bs[2][128 * 32];
  const int tid = threadIdx.x;
  const int lane = tid & 63;
  const int wid = tid >> 6;
  const int wr = wid >> 1, wc = wid & 1;
  const int l16 = lane & 15, kq = lane >> 4;
  const int m0 = blockIdx.x * 128;
  const int n0 = blockIdx.y * 128;

  f32x4 acc[4][4];
#pragma unroll
  for (int i = 0; i < 4; ++i)
#pragma unroll
    for (int j = 0; j < 4; ++j) acc[i][j] = (f32x4){0.f, 0.f, 0.f, 0.f};

  const int srow = tid >> 2;
  const int skg = tid & 3;
  const int scol = (skg ^ ((srow >> 1) & 3)) * 8;  // pre-swizzled source col
  const int sbase = (tid & ~63) * 8;               // wave-uniform LDS elem base

  const unsigned short* Ag = A + (size_t)(m0 + srow) * K + scol;
  const unsigned short* Bg = B + (size_t)(n0 + srow) * K + scol;
  const int kqA0 = (kq ^ ((l16 >> 1) & 3)) * 8;    // swizzled k-group for reads

#define STAGE(buf, kk)                                                                              \
  do {                                                                                              \
    __builtin_amdgcn_global_load_lds((const __attribute__((address_space(1))) void*)(Ag + (kk)),    \
                                     (__attribute__((address_space(3))) void*)(&As[buf][0] + sbase), 16, 0, 0); \
    __builtin_amdgcn_global_load_lds((const __attribute__((address_space(1))) void*)(Ag + (size_t)64 * K + (kk)), \
                                     (__attribute__((address_space(3))) void*)(&As[buf][0] + 2048 + sbase), 16, 0, 0); \
    __builtin_amdgcn_global_load_lds((const __attribute__((address_space(1))) void*)(Bg + (kk)),    \
                                     (__attribute__((address_space(3))) void*)(&Bs[buf][0] + sbase), 16, 0, 0); \
    __builtin_amdgcn_global_load_lds((const __attribute__((address_space(1))) void*)(Bg + (size_t)64 * K + (kk)), \
                                     (__attribute__((address_space(3))) void*)(&Bs[buf][0] + 2048 + sbase), 16, 0, 0); \
  } while (0)

  STAGE(0, 0);
  __syncthreads();
  int cur = 0;
  for (int k0 = 0; k0 < K; k0 += 32) {
    if (k0 + 32 < K) STAGE(cur ^ 1, k0 + 32);  // prefetch overlaps compute
    bf16x8 af[4], bfr[4];
#pragma unroll
    for (int i = 0; i < 4; ++i) {
      int ra = wr * 64 + i * 16 + l16;
      af[i] = *(const bf16x8*)(&As[cur][0] + ra * 32 + kqA0);
      int rb = wc * 64 + i * 16 + l16;
      bfr[i] = *(const bf16x8*)(&Bs[cur][0] + rb * 32 + kqA0);
    }
#pragma unroll
    for (int mi = 0; mi < 4; ++mi)
#pragma unroll
      for (int ni = 0; ni < 4; ++ni)
        acc[mi][ni] = __builtin_amdgcn_mfma_f32_16x16x32_bf16(af[mi], bfr[ni], acc[mi][ni], 0, 0, 0);
    __syncthreads();
    cur ^= 1;
  }
#undef STAGE

  float* Cf = (float*)Cv;
  unsigned short* Cb = (unsigned short*)Cv;
#pragma unroll
  for (int mi = 0; mi < 4; ++mi) {
    int grow = m0 + wr * 64 + mi * 16 + kq * 4;
#pragma unroll
    for (int ni = 0; ni < 4; ++ni) {
      int gcol = n0 + wc * 64 + ni * 16 + l16;
      float bv_ = bias[gcol];
#pragma unroll
      for (int r = 0; r < 4; ++r) {
        float v = acc[mi][ni][r] + bv_;
        if (OUT_F32)
          Cf[(size_t)(grow + r) * Nn + gcol] = v;
        else
          Cb[(size_t)(grow + r) * Nn + gcol] = f2b(v);
      }
    }
  }
}

// ---------------- rowptr from sorted row_idx ----------------
__global__ __launch_bounds__(256) void build_rowptr(const int* __restrict__ row_idx,
                                                    int* __restrict__ rowptr, int n, int E_) {
  int t = blockIdx.x * 256 + threadIdx.x;
  if (t > n) return;
  int lo = 0, hi = E_;
  while (lo < hi) {
    int mid = (lo + hi) >> 1;
    if (row_idx[mid] < t) lo = mid + 1; else hi = mid;
  }
  rowptr[t] = lo;
}

// ---------------- pass A: edge-centric SDDMM (per head) ----------------
// Wave handles 128 consecutive edges for one head: 8 iters x (2 groups of 8 edges).
// Group g = edge, lane dl = dims dl*8..+8. q gathered per edge (row_idx sorted ->
// L1-hot sequential repeats); k gathered random within the 4.2MB head plane (L2-hot).
__global__ __launch_bounds__(256) void sddmm_ec(const int* __restrict__ row_idx,
                                                const int* __restrict__ col_idx,
                                                const unsigned short* __restrict__ q,
                                                const unsigned short* __restrict__ kv,
                                                float* __restrict__ scores, int E_) {
  int head = blockIdx.y;
  int lane = threadIdx.x & 63;
  int wid = threadIdx.x >> 6;
  int g = lane >> 3, dl = lane & 7;
  const unsigned short* qbase = q + head * HD + dl * 8;
  const unsigned short* kbase = kv + head * HD + dl * 8;
  float* sc = scores + (size_t)head * E_;
  int e00 = blockIdx.x * 512 + wid * 128;
#pragma unroll
  for (int it = 0; it < 8; ++it) {
    int ea = e00 + it * 16 + g;
    int eb = ea + 8;
    int eac = ea < E_ ? ea : E_ - 1;
    int ebc = eb < E_ ? eb : E_ - 1;
    int ra = row_idx[eac], ca = col_idx[eac];
    int rb = row_idx[ebc], cb = col_idx[ebc];
    bf16x8 qa = *(const bf16x8*)(qbase + (size_t)ra * HID);
    bf16x8 ka = *(const bf16x8*)(kbase + (size_t)ca * (2 * HID));
    bf16x8 qb2 = *(const bf16x8*)(qbase + (size_t)rb * HID);
    bf16x8 kb = *(const bf16x8*)(kbase + (size_t)cb * (2 * HID));
    float da = 0.f, db = 0.f;
#pragma unroll
    for (int i = 0; i < 8; ++i) {
      da += b2f((unsigned short)qa[i]) * b2f((unsigned short)ka[i]);
      db += b2f((unsigned short)qb2[i]) * b2f((unsigned short)kb[i]);
    }
    da += __shfl_xor(da, 1); db += __shfl_xor(db, 1);
    da += __shfl_xor(da, 2); db += __shfl_xor(db, 2);
    da += __shfl_xor(da, 4); db += __shfl_xor(db, 4);
    if (dl == 0) {
      if (ea < E_) sc[ea] = da;
      if (eb < E_) sc[eb] = db;
    }
  }
}

// ---------------- pass B: per (row, head-pair) wave; inline max/sum; weighted v-gather ----------------
// 64 lanes = 2 head-halves x (4 edge-groups x 8 dims). Segment scores are contiguous:
// max & exp-sum via strided coalesced sweeps (avg degree 32 -> ~1 iter each).
__global__ __launch_bounds__(256) void edge_spmm2(const int* __restrict__ rowptr,
                                                  const int* __restrict__ col_idx,
                                                  const float* __restrict__ scores,
                                                  const unsigned short* __restrict__ kv,
                                                  unsigned short* __restrict__ out, int n, int E_) {
  int lane = threadIdx.x & 63;
  int row = blockIdx.x * 4 + (threadIdx.x >> 6);
  if (row >= n) return;
  int hh = lane >> 5;
  int head = blockIdx.y * 2 + hh;
  int hl = lane & 31;
  int g = hl >> 3, dl = hl & 7;
  int s0 = rowptr[row], s1 = rowptr[row + 1];
  const float* sc = scores + (size_t)head * E_;

  float m = -1e30f;
  for (int e = s0 + hl; e < s1; e += 32) m = fmaxf(m, sc[e]);
  m = fmaxf(m, __shfl_xor(m, 1));
  m = fmaxf(m, __shfl_xor(m, 2));
  m = fmaxf(m, __shfl_xor(m, 4));
  m = fmaxf(m, __shfl_xor(m, 8));
  m = fmaxf(m, __shfl_xor(m, 16));
  float sm = 0.f;
  for (int e = s0 + hl; e < s1; e += 32) sm += EXP2(sc[e] - m);
  sm += __shfl_xor(sm, 1);
  sm += __shfl_xor(sm, 2);
  sm += __shfl_xor(sm, 4);
  sm += __shfl_xor(sm, 8);
  sm += __shfl_xor(sm, 16);
  float inv = (sm > 0.f) ? 1.f / sm : 0.f;

  const unsigned short* vbase = kv + HID + head * HD + dl * 8;
  float acc[8] = {};
  int e0 = s0;
  for (; e0 + 8 <= s1; e0 += 8) {
    int ea = e0 + g, eb = e0 + 4 + g;
    int ca = col_idx[ea], cb = col_idx[eb];
    float wa = EXP2(sc[ea] - m) * inv;
    float wb = EXP2(sc[eb] - m) * inv;
    bf16x8 va = *(const bf16x8*)(vbase + (size_t)ca * (2 * HID));
    bf16x8 vb = *(const bf16x8*)(vbase + (size_t)cb * (2 * HID));
#pragma unroll
    for (int i = 0; i < 8; ++i) {
      acc[i] += wa * b2f((unsigned short)va[i]);
      acc[i] += wb * b2f((unsigned short)vb[i]);
    }
  }
  for (; e0 < s1; e0 += 4) {
    int ea = e0 + g;
    bool valid = ea < s1;
    int ec = valid ? ea : (E_ - 1);
    int c = col_idx[ec];
    float w = valid ? EXP2(sc[ec] - m) * inv : 0.f;
    bf16x8 vc = *(const bf16x8*)(vbase + (size_t)c * (2 * HID));
#pragma unroll
    for (int i = 0; i < 8; ++i) acc[i] += w * b2f((unsigned short)vc[i]);
  }
#pragma unroll
  for (int i = 0; i < 8; ++i) {
    acc[i] += __shfl_xor(acc[i], 8);
    acc[i] += __shfl_xor(acc[i], 16);
  }
  if (g == 0) {
    short o[8];
#pragma unroll
    for (int i = 0; i < 8; ++i) o[i] = (short)f2b(acc[i]);
    *(bf16x8*)(out + (size_t)row * HID + head * HD + dl * 8) = *(bf16x8*)o;
  }
}

// ---------------- launch ----------------
extern "C" void kernel_launch(void* const* d_in, const int* in_sizes, int n_in,
                              void* d_out, int out_size, void* d_ws, size_t ws_size,
                              hipStream_t stream) {
  const float* h_source = (const float*)d_in[0];
  const float* h_target = (const float*)d_in[1];
  const int* row_idx = (const int*)d_in[2];
  const int* col_idx = (const int*)d_in[3];
  const float* Wq = (const float*)d_in[4];
  const float* bq = (const float*)d_in[5];
  const float* Wk = (const float*)d_in[6];
  const float* bk = (const float*)d_in[7];
  const float* Wv = (const float*)d_in[8];
  const float* bv = (const float*)d_in[9];
  const float* Wo = (const float*)d_in[10];
  const float* bo = (const float*)d_in[11];
  float* out = (float*)d_out;

  const int n = in_sizes[0] / HID;   // 32768
  const int E_ = in_sizes[2];        // 1048576

  char* ws = (char*)d_ws;
  size_t off = 0;
  auto alloc = [&](size_t bytes) -> void* {
    off = (off + 255) & ~(size_t)255;
    void* p = ws + off;
    off += bytes;
    return p;
  };
  unsigned short* htb = (unsigned short*)alloc((size_t)n * HID * 2);   // h_target bf16
  unsigned short* hsb = (unsigned short*)alloc((size_t)n * HID * 2);   // h_source bf16
  unsigned short* qb = (unsigned short*)alloc((size_t)n * HID * 2);    // q; attn_out in-place
  unsigned short* kvb = (unsigned short*)alloc((size_t)n * 2 * HID * 2);  // kv interleaved
  float* scores = (float*)alloc((size_t)NH * E_ * 4);                  // per-head planes
  unsigned short* wqp = (unsigned short*)alloc((size_t)HID * HID * 2);
  unsigned short* wkvp = (unsigned short*)alloc((size_t)2 * HID * HID * 2);
  unsigned short* wop = (unsigned short*)alloc((size_t)HID * HID * 2);
  float* bqp = (float*)alloc(HID * 4);
  float* bkvp = (float*)alloc(2 * HID * 4);
  int* rowptr = (int*)alloc((size_t)(n + 1) * 4);

  int n4 = n * HID / 4;
  cast_bf16<<<(n4 + 255) / 256, 256, 0, stream>>>(h_target, htb, n4);
  cast_bf16<<<(n4 + 255) / 256, 256, 0, stream>>>(h_source, hsb, n4);
  prep_weights<<<dim3(HID * HID / 256, 4), 256, 0, stream>>>(Wq, Wk, Wv, Wo, wqp, wkvp, wop);
  prep_bias<<<1, HID, 0, stream>>>(bq, bk, bv, bqp, bkvp);
  build_rowptr<<<(n + 1 + 255) / 256, 256, 0, stream>>>(row_idx, rowptr, n, E_);

  dim3 gq(n / 128, HID / 128);
  dim3 gkv(n / 128, 2 * HID / 128);
  gemm_nt<0><<<gq, 256, 0, stream>>>(htb, wqp, bqp, qb, n, HID, HID);
  gemm_nt<0><<<gkv, 256, 0, stream>>>(hsb, wkvp, bkvp, kvb, n, 2 * HID, HID);

  dim3 ga((E_ + 511) / 512, NH);
  sddmm_ec<<<ga, 256, 0, stream>>>(row_idx, col_idx, qb, kvb, scores, E_);
  dim3 gb(n / 4, NH / 2);
  edge_spmm2<<<gb, 256, 0, stream>>>(rowptr, col_idx, scores, kvb, qb /* attn_out */, n, E_);

  gemm_nt<1><<<gq, 256, 0, stream>>>(qb, wop, bo, out, n, HID, HID);
}